// Round 6
// baseline (207.915 us; speedup 1.0000x reference)
//
#include <hip/hip_runtime.h>
#include <math.h>

#define BATCH 8
#define NN 2048
#define DIN 256
#define RANK 64
#define TOPKK 32
#define CANDMAX 96

static constexpr size_t A_ELEMS = (size_t)BATCH * NN * NN;   // 33554432
static constexpr size_t S_OFF   = A_ELEMS;
static constexpr size_t R_OFF   = 2 * A_ELEMS;
static constexpr size_t NROWS   = (size_t)BATCH * NN;        // 16384

// ws layout (float offsets)
static constexpr size_t G_OFF      = 0;                       // G[8][4096]
static constexpr size_t U_OFF      = 32768;                   // u[8][64]
static constexpr size_t GP_OFF     = 33280;                   // Gpart[64][4160]
static constexpr size_t CNT_OFF_F  = GP_OFF + 64 * 4160;      // cnt[16384] (int)
static constexpr size_t CAND_OFF_F = CNT_OFF_F + NROWS;       // byte offset 8-aligned
// cand: u64[NROWS][CANDMAX] = 12.6 MB; total ws ~13.9 MB

#define NEG_INF (-__builtin_inff())

// ---------------- threefry2x32, JAX partitionable counter-mode (verified r3) ----------------
__device__ __forceinline__ unsigned rotl32(unsigned x, int d) {
  return (x << d) | (x >> (32 - d));
}

__device__ unsigned threefry_bits(unsigned flat) {
  const unsigned ks0 = 0u, ks1 = 42u, ks2 = 0u ^ 42u ^ 0x1BD11BDAu;
  unsigned x0 = 0u + ks0;
  unsigned x1 = flat + ks1;
#define TF_ROUND(r) { x0 += x1; x1 = rotl32(x1, r); x1 ^= x0; }
  TF_ROUND(13) TF_ROUND(15) TF_ROUND(26) TF_ROUND(6)
  x0 += ks1; x1 += ks2 + 1u;
  TF_ROUND(17) TF_ROUND(29) TF_ROUND(16) TF_ROUND(24)
  x0 += ks2; x1 += ks0 + 2u;
  TF_ROUND(13) TF_ROUND(15) TF_ROUND(26) TF_ROUND(6)
  x0 += ks0; x1 += ks1 + 3u;
  TF_ROUND(17) TF_ROUND(29) TF_ROUND(16) TF_ROUND(24)
  x0 += ks1; x1 += ks2 + 4u;
  TF_ROUND(13) TF_ROUND(15) TF_ROUND(26) TF_ROUND(6)
  x0 += ks2; x1 += ks0 + 5u;
#undef TF_ROUND
  return x0 ^ x1;
}

__device__ __forceinline__ unsigned long long make_key(float v, int col) {
  unsigned u = __float_as_uint(v);
  u = (u & 0x80000000u) ? ~u : (u | 0x80000000u);
  return ((unsigned long long)u << 32) | (unsigned)(~col);
}

__device__ __forceinline__ void decode_key(unsigned long long key, float& val, int& col) {
  unsigned hi = (unsigned)(key >> 32);
  unsigned ub = (hi & 0x80000000u) ? (hi ^ 0x80000000u) : ~hi;
  val = __uint_as_float(ub);
  col = (int)(~(unsigned)key) & (NN - 1);
}

// lane MUST be the within-wave lane id (threadIdx.x & 63), not threadIdx.x!
__device__ __forceinline__ void bitonic64_desc(unsigned long long& key, int lane) {
#pragma unroll
  for (int k = 2; k <= 64; k <<= 1) {
#pragma unroll
    for (int j = k >> 1; j >= 1; j >>= 1) {
      unsigned long long o = __shfl_xor(key, j, 64);
      bool lower = (lane & j) == 0;
      bool desc  = (lane & k) == 0;
      bool takeMax = (lower == desc);
      bool kgo = key > o;
      key = (takeMax == kgo) ? key : o;
    }
  }
}

// ---------------- kernel 1: R = X*W ; T = (R*B)/8 (verified r4) ----------------
__global__ __launch_bounds__(256) void rt_kernel(const float* __restrict__ X,
                                                 const float* __restrict__ W,
                                                 const float* __restrict__ Bm,
                                                 float* __restrict__ out) {
  __shared__ float Xs[32][256];
  __shared__ float Bs[64][64];
  __shared__ float Rs[32][64];
  const int t = threadIdx.x;
  const int blk = blockIdx.x;
  const int b  = blk >> 6;
  const int rb = blk & 63;
  const float* Xb = X + ((size_t)b * NN + (size_t)rb * 32) * DIN;

#pragma unroll
  for (int it = 0; it < 8; ++it) {
    int flat = it * 1024 + t * 4;
    *(float4*)&Xs[flat >> 8][flat & 255] = *(const float4*)(Xb + flat);
  }
#pragma unroll
  for (int it = 0; it < 4; ++it) {
    int flat = it * 1024 + t * 4;
    *(float4*)&Bs[flat >> 6][flat & 63] = *(const float4*)(Bm + flat);
  }
  __syncthreads();

  const int j = t & 63, rg = t >> 6;
  float acc[8] = {0.f, 0.f, 0.f, 0.f, 0.f, 0.f, 0.f, 0.f};
  for (int k = 0; k < DIN; k += 4) {
    float w0 = W[(k + 0) * RANK + j];
    float w1 = W[(k + 1) * RANK + j];
    float w2 = W[(k + 2) * RANK + j];
    float w3 = W[(k + 3) * RANK + j];
#pragma unroll
    for (int ii = 0; ii < 8; ++ii) {
      float4 xv = *(const float4*)&Xs[rg * 8 + ii][k];
      acc[ii] += xv.x * w0 + xv.y * w1 + xv.z * w2 + xv.w * w3;
    }
  }
  const size_t grow0 = (size_t)b * NN + (size_t)rb * 32;
  float* Rout = out + R_OFF + grow0 * RANK;
#pragma unroll
  for (int ii = 0; ii < 8; ++ii) {
    Rout[(size_t)(rg * 8 + ii) * RANK + j] = acc[ii];
    Rs[rg * 8 + ii][j] = acc[ii];
  }
  __syncthreads();

  float acc2[8] = {0.f, 0.f, 0.f, 0.f, 0.f, 0.f, 0.f, 0.f};
  for (int r = 0; r < RANK; r += 4) {
    float b0 = Bs[r + 0][j];
    float b1 = Bs[r + 1][j];
    float b2 = Bs[r + 2][j];
    float b3 = Bs[r + 3][j];
#pragma unroll
    for (int ii = 0; ii < 8; ++ii) {
      float4 rv = *(const float4*)&Rs[rg * 8 + ii][r];
      acc2[ii] += rv.x * b0 + rv.y * b1 + rv.z * b2 + rv.w * b3;
    }
  }
  float* Tout = out + grow0 * RANK;   // T scratch in A region
#pragma unroll
  for (int ii = 0; ii < 8; ++ii)
    Tout[(size_t)(rg * 8 + ii) * RANK + j] = acc2[ii] * 0.125f;
}

// ---------------- kernel 2a: partial G = R^T R, u = sum rows (per batch, 8 k-chunks) ----------------
__global__ __launch_bounds__(256) void ga_kernel(const float* __restrict__ out,
                                                 float* __restrict__ ws) {
  __shared__ float Rl[128][68];
  const int t = threadIdx.x;
  const int b = blockIdx.x >> 3, chunk = blockIdx.x & 7;
  const float* Rb = out + R_OFF + ((size_t)b * NN + (size_t)chunk * 256) * RANK;
  const int i0 = (t >> 4) * 4, j0 = (t & 15) * 4;
  float acc[4][4];
#pragma unroll
  for (int a = 0; a < 4; ++a)
#pragma unroll
    for (int c = 0; c < 4; ++c) acc[a][c] = 0.f;
  float uacc = 0.f;

  for (int s2 = 0; s2 < 2; ++s2) {
    const float* src = Rb + (size_t)s2 * 128 * RANK;
#pragma unroll
    for (int it = 0; it < 8; ++it) {
      int flat = it * 1024 + t * 4;
      *(float4*)&Rl[flat >> 6][flat & 63] = *(const float4*)(src + flat);
    }
    __syncthreads();
    for (int r = 0; r < 128; ++r) {
      float4 a = *(const float4*)&Rl[r][i0];
      float4 bb = *(const float4*)&Rl[r][j0];
      acc[0][0] = fmaf(a.x, bb.x, acc[0][0]); acc[0][1] = fmaf(a.x, bb.y, acc[0][1]);
      acc[0][2] = fmaf(a.x, bb.z, acc[0][2]); acc[0][3] = fmaf(a.x, bb.w, acc[0][3]);
      acc[1][0] = fmaf(a.y, bb.x, acc[1][0]); acc[1][1] = fmaf(a.y, bb.y, acc[1][1]);
      acc[1][2] = fmaf(a.y, bb.z, acc[1][2]); acc[1][3] = fmaf(a.y, bb.w, acc[1][3]);
      acc[2][0] = fmaf(a.z, bb.x, acc[2][0]); acc[2][1] = fmaf(a.z, bb.y, acc[2][1]);
      acc[2][2] = fmaf(a.z, bb.z, acc[2][2]); acc[2][3] = fmaf(a.z, bb.w, acc[2][3]);
      acc[3][0] = fmaf(a.w, bb.x, acc[3][0]); acc[3][1] = fmaf(a.w, bb.y, acc[3][1]);
      acc[3][2] = fmaf(a.w, bb.z, acc[3][2]); acc[3][3] = fmaf(a.w, bb.w, acc[3][3]);
    }
    if (t < 64) {
      for (int r = 0; r < 128; ++r) uacc += Rl[r][t];
    }
    __syncthreads();
  }
  float* dst = ws + GP_OFF + (size_t)blockIdx.x * 4160;
#pragma unroll
  for (int a = 0; a < 4; ++a) {
    float4 f = make_float4(acc[a][0], acc[a][1], acc[a][2], acc[a][3]);
    *(float4*)&dst[(i0 + a) * 64 + j0] = f;
  }
  if (t < 64) dst[4096 + t] = uacc;
}

// ---------------- kernel 2b: deterministic reduction of G/u partials ----------------
__global__ __launch_bounds__(256) void gb_kernel(float* __restrict__ ws) {
  const int b = blockIdx.x, t = threadIdx.x;
  for (int idx = t; idx < 4160; idx += 256) {
    float s = 0.f;
    for (int c = 0; c < 8; ++c)
      s += ws[GP_OFF + (size_t)(b * 8 + c) * 4160 + idx];
    if (idx < 4096) ws[G_OFF + (size_t)b * 4096 + idx] = s;
    else            ws[U_OFF + (size_t)b * 64 + (idx - 4096)] = s;
  }
}

// ---------------- kernel 3: fused S-GEMM + threshold screen -> S, cand, cnt ----------------
__global__ __launch_bounds__(512) void fuseda_kernel(float* __restrict__ out,
                                                     float* __restrict__ ws) {
  __shared__ float Tk[64][64];    // k-major T panel
  __shared__ float Rk[64][128];   // k-major R tile
  __shared__ float u_l[64];
  __shared__ float tau_l[64];
  __shared__ int   cnt_l[64];

  const int t = threadIdx.x;
  const int bid = blockIdx.x;
  const int b = bid >> 5, p = bid & 31;
  const int n0 = p * 64;
  const size_t g0 = (size_t)b * NN + n0;

  const float* Tsrc = out + g0 * RANK;                    // T scratch (A region)
  const float* Rsrc = out + R_OFF + (size_t)b * NN * RANK;
  float* Sbase = out + S_OFF + (size_t)b * NN * NN;
  unsigned long long* cand = (unsigned long long*)(ws + CAND_OFF_F);
  int* cnt_ws = (int*)(ws + CNT_OFF_F);

  // Phase 0: stage T (k-major) + u
#pragma unroll
  for (int it = 0; it < 2; ++it) {
    int flat = it * 2048 + t * 4;
    int r = flat >> 6, k0 = flat & 63;
    float4 f = *(const float4*)(Tsrc + flat);
    Tk[k0 + 0][r] = f.x; Tk[k0 + 1][r] = f.y;
    Tk[k0 + 2][r] = f.z; Tk[k0 + 3][r] = f.w;
  }
  if (t < 64) { u_l[t] = ws[U_OFF + (size_t)b * 64 + t]; cnt_l[t] = 0; }
  __syncthreads();

  // Phase 0b: per-row stats -> tau (exact mu, sigma via u and G)
  {
    const int wave = t >> 6, lane = t & 63;
    const float* Gb = ws + G_OFF + (size_t)b * 4096;
    for (int q = 0; q < 8; ++q) {
      int row = wave * 8 + q;
      float gj = 0.f, mua = 0.f;
      for (int k = 0; k < 64; ++k) {
        float tk = Tk[k][row];                 // uniform -> LDS broadcast
        gj  = fmaf(tk, Gb[k * 64 + lane], gj); // coalesced L2 read
        mua = fmaf(tk, u_l[k], mua);
      }
      float tj = Tk[lane][row];
      float qq = gj * tj;
#pragma unroll
      for (int off = 1; off < 64; off <<= 1) qq += __shfl_xor(qq, off, 64);
      float ms = qq * (1.f / 2048.f);
      float mu = mua * (1.f / 2048.f);
      float sigma = sqrtf(fmaxf(ms - mu * mu, 1e-12f));
      if (lane == 0) tau_l[row] = mu + 1.8627f * sigma;  // target ~64 cands
    }
  }
  __syncthreads();

  const int tx = t & 31, ty = t >> 5;   // cols tx*4.., rows ty*4..
  float taur[4];
#pragma unroll
  for (int i = 0; i < 4; ++i) taur[i] = tau_l[ty * 4 + i];

  float4 pf[4];
#define STAGE_ISSUE(tile) {                                                  \
  _Pragma("unroll")                                                          \
  for (int it = 0; it < 4; ++it) {                                           \
    int flat = it * 2048 + t * 4;                                            \
    int c = flat >> 6, k0 = flat & 63;                                       \
    pf[it] = *(const float4*)(Rsrc + (size_t)((tile) * 128 + c) * RANK + k0);\
  } }
#define STAGE_WRITE() {                                                      \
  _Pragma("unroll")                                                          \
  for (int it = 0; it < 4; ++it) {                                           \
    int flat = it * 2048 + t * 4;                                            \
    int c = flat >> 6, k0 = flat & 63;                                       \
    Rk[k0 + 0][c] = pf[it].x; Rk[k0 + 1][c] = pf[it].y;                      \
    Rk[k0 + 2][c] = pf[it].z; Rk[k0 + 3][c] = pf[it].w;                      \
  } }

  STAGE_ISSUE(0); STAGE_WRITE();
  __syncthreads();

  for (int tile = 0; tile < 16; ++tile) {
    if (tile < 15) STAGE_ISSUE(tile + 1);

    float4 accv[4];
#pragma unroll
    for (int i = 0; i < 4; ++i) accv[i] = make_float4(0.f, 0.f, 0.f, 0.f);
    for (int k = 0; k < 64; ++k) {
      float4 a  = *(const float4*)&Tk[k][ty * 4];
      float4 bb = *(const float4*)&Rk[k][tx * 4];
      accv[0].x = fmaf(a.x, bb.x, accv[0].x); accv[0].y = fmaf(a.x, bb.y, accv[0].y);
      accv[0].z = fmaf(a.x, bb.z, accv[0].z); accv[0].w = fmaf(a.x, bb.w, accv[0].w);
      accv[1].x = fmaf(a.y, bb.x, accv[1].x); accv[1].y = fmaf(a.y, bb.y, accv[1].y);
      accv[1].z = fmaf(a.y, bb.z, accv[1].z); accv[1].w = fmaf(a.y, bb.w, accv[1].w);
      accv[2].x = fmaf(a.z, bb.x, accv[2].x); accv[2].y = fmaf(a.z, bb.y, accv[2].y);
      accv[2].z = fmaf(a.z, bb.z, accv[2].z); accv[2].w = fmaf(a.z, bb.w, accv[2].w);
      accv[3].x = fmaf(a.w, bb.x, accv[3].x); accv[3].y = fmaf(a.w, bb.y, accv[3].y);
      accv[3].z = fmaf(a.w, bb.z, accv[3].z); accv[3].w = fmaf(a.w, bb.w, accv[3].w);
    }

    // write S + threshold insert
#pragma unroll
    for (int i = 0; i < 4; ++i) {
      int rl = ty * 4 + i;
      int grow = n0 + rl;
      *(float4*)(Sbase + (size_t)grow * NN + tile * 128 + tx * 4) = accv[i];
      const float vv[4] = {accv[i].x, accv[i].y, accv[i].z, accv[i].w};
#pragma unroll
      for (int jj = 0; jj < 4; ++jj) {
        int col = tile * 128 + tx * 4 + jj;
        float v = vv[jj];
        if (col != grow && v > taur[i]) {
          int pos = atomicAdd(&cnt_l[rl], 1);
          if (pos < CANDMAX)
            cand[(g0 + rl) * CANDMAX + pos] = make_key(v, col);
        }
      }
    }
    __syncthreads();
    if (tile < 15) { STAGE_WRITE(); }
    __syncthreads();
  }
#undef STAGE_ISSUE
#undef STAGE_WRITE

  if (t < 64) cnt_ws[g0 + t] = cnt_l[t];
}

// ---------------- kernel 4: sort cands -> top-32 -> softmax/dropout -> A ----------------
__global__ __launch_bounds__(256) void fusedb_kernel(float* __restrict__ out,
                                                     const float* __restrict__ ws) {
  __shared__ unsigned long long wbuf[4][64];
  __shared__ int fcnt[4];
  __shared__ float rowbuf[4][2048];          // 32 KB, one row per wave
  const int t = threadIdx.x;
  const int wv = t >> 6, lane = t & 63;
  const int g = blockIdx.x * 4 + wv;         // global row
  const int n = g & (NN - 1);

  const unsigned long long* crow =
      (const unsigned long long*)(ws + CAND_OFF_F) + (size_t)g * CANDMAX;
  const int c = ((const int*)(ws + CNT_OFF_F))[g];

  unsigned long long key = 0ull;
  if (c >= TOPKK && c <= CANDMAX) {
    if (c <= 64) {
      key = (lane < c) ? crow[lane] : 0ull;
      bitonic64_desc(key, lane);
    } else {
      key = crow[lane];
      bitonic64_desc(key, lane);
      // keep top-32; refill lanes 32..63 with the tail, sort again (full network)
      if (lane >= 32) { int idx = 64 + (lane - 32); key = (idx < c) ? crow[idx] : 0ull; }
      bitonic64_desc(key, lane);
    }
  } else {
    // ---- rare fallback: exact re-screen of the full S row ----
    const float* row = out + S_OFF + (size_t)g * NN;
    float v[32];
#pragma unroll
    for (int jj = 0; jj < 8; ++jj) {
      float4 f = *(const float4*)(row + jj * 256 + lane * 4);
      v[jj * 4 + 0] = f.x; v[jj * 4 + 1] = f.y;
      v[jj * 4 + 2] = f.z; v[jj * 4 + 3] = f.w;
    }
    float s = 0.f, ss = 0.f;
#pragma unroll
    for (int jj = 0; jj < 32; ++jj) { s += v[jj]; ss = fmaf(v[jj], v[jj], ss); }
#pragma unroll
    for (int off = 1; off < 64; off <<= 1) {
      s += __shfl_xor(s, off, 64); ss += __shfl_xor(ss, off, 64);
    }
    const float mu = s * (1.f / 2048.f);
    const float sigma = sqrtf(fmaxf(ss * (1.f / 2048.f) - mu * mu, 1e-12f));
    {
      int d = n - lane * 4;
      if (d >= 0 && d < NN && (d & 255) < 4) v[((d >> 8) << 2) | (d & 3)] = NEG_INF;
    }
    float tau = mu + 2.0641f * sigma;
    float lo_b = -3.0e38f, hi_b = 3.0e38f;
    float step = sigma + 1e-20f;
    bool found = false;
    for (int it = 0; it < 40; ++it) {
      int cl = 0;
#pragma unroll
      for (int jj = 0; jj < 32; ++jj) cl += (v[jj] > tau) ? 1 : 0;
#pragma unroll
      for (int off = 1; off < 64; off <<= 1) cl += __shfl_xor(cl, off, 64);
      if (cl >= TOPKK && cl <= 64) { found = true; break; }
      if (cl > 64) lo_b = fmaxf(lo_b, tau); else hi_b = fminf(hi_b, tau);
      float tn = 0.f; bool ok = false;
      if (it < 6) {
        float pp = fminf(fmaxf((float)cl, 1.f) * (1.f / 2048.f), 0.5f);
        float tt = sqrtf(-2.f * logf(pp));
        float zc = tt - (2.30753f + 0.27061f * tt) /
                        (1.f + tt * (0.99229f + 0.04481f * tt));
        zc = fmaxf(zc, 0.05f);
        tn = mu + 2.0641f * ((tau - mu) / zc);
        ok = (tn > lo_b && tn < hi_b);
      }
      if (!ok) {
        if (lo_b > -1.0e38f && hi_b < 1.0e38f) tn = 0.5f * lo_b + 0.5f * hi_b;
        else if (cl > 64) { tn = tau + step; step *= 2.f; }
        else              { tn = tau - step; step *= 2.f; }
      }
      tau = tn;
    }
    if (found) {
      if (lane == 0) fcnt[wv] = 0;
      int mycnt = 0;
#pragma unroll
      for (int jj = 0; jj < 32; ++jj) {
        if (v[jj] > tau) {
          int col = ((jj >> 2) << 8) + lane * 4 + (jj & 3);
          int pos = atomicAdd(&fcnt[wv], 1);
          wbuf[wv][pos] = make_key(v[jj], col);
          ++mycnt;
        }
      }
      int fc = mycnt;
#pragma unroll
      for (int off = 1; off < 64; off <<= 1) fc += __shfl_xor(fc, off, 64);
      key = (lane < fc) ? wbuf[wv][lane] : 0ull;
      bitonic64_desc(key, lane);
    } else {
      // exact serial extraction (ties-exact; measure-zero path)
      unsigned alive = 0xFFFFFFFFu;
      unsigned long long keysel = 0ull;
      for (int it = 0; it < TOPKK; ++it) {
        unsigned long long best = 0ull;
#pragma unroll
        for (int jj = 0; jj < 32; ++jj) {
          if ((alive >> jj) & 1u) {
            int col = ((jj >> 2) << 8) + lane * 4 + (jj & 3);
            unsigned long long kk = make_key(v[jj], col);
            if (kk > best) best = kk;
          }
        }
        unsigned long long b2 = best;
#pragma unroll
        for (int off = 1; off < 64; off <<= 1) {
          unsigned long long o = __shfl_xor(b2, off, 64);
          if (o > b2) b2 = o;
        }
        if (lane == it) keysel = b2;
        if (best == b2) {
#pragma unroll
          for (int jj = 0; jj < 32; ++jj) {
            int col = ((jj >> 2) << 8) + lane * 4 + (jj & 3);
            if (make_key(v[jj], col) == b2) alive &= ~(1u << jj);
          }
        }
      }
      key = keysel;   // lanes 0..31 already sorted desc
    }
  }

  // ---- common epilogue: lanes 0..31 hold top-32 sorted desc ----
  float val; int col;
  decode_key(key, val, col);

  float m = __shfl(val, 0, 64);
  float e = (lane < TOPKK) ? expf(val - m) : 0.f;
  float s1 = e;
#pragma unroll
  for (int off = 1; off < 64; off <<= 1) s1 += __shfl_xor(s1, off, 64);
  float a1 = e / fmaxf(s1, 1e-6f);

  float a2 = 0.f;
  if (lane < TOPKK) {
    unsigned flat = (unsigned)g * 2048u + (unsigned)col;
    unsigned bits = threefry_bits(flat);
    float u = __uint_as_float((bits >> 9) | 0x3f800000u) - 1.0f;
    if (u <= 0.9f) a2 = a1 * (1.f / 0.9f);
  }
  float s2 = a2;
#pragma unroll
  for (int off = 1; off < 64; off <<= 1) s2 += __shfl_xor(s2, off, 64);
  float av = a2 / fmaxf(s2, 1e-6f);

  // ---- materialize row via LDS (r4-verified path) ----
#pragma unroll
  for (int jj = 0; jj < 8; ++jj)
    *(float4*)&rowbuf[wv][jj * 256 + lane * 4] = make_float4(0.f, 0.f, 0.f, 0.f);
  __syncthreads();
  if (lane < TOPKK) rowbuf[wv][col] = av;
  __syncthreads();
  float* Arow = out + (size_t)g * NN;
#pragma unroll
  for (int jj = 0; jj < 8; ++jj)
    *(float4*)(Arow + jj * 256 + lane * 4) = *(float4*)&rowbuf[wv][jj * 256 + lane * 4];
}

extern "C" void kernel_launch(void* const* d_in, const int* in_sizes, int n_in,
                              void* d_out, int out_size, void* d_ws, size_t ws_size,
                              hipStream_t stream) {
  const float* X  = (const float*)d_in[0];
  const float* W  = (const float*)d_in[1];
  const float* Bm = (const float*)d_in[2];
  float* out = (float*)d_out;
  float* ws  = (float*)d_ws;   // ~13.9 MB used

  hipLaunchKernelGGL(rt_kernel, dim3(512), dim3(256), 0, stream, X, W, Bm, out);
  hipLaunchKernelGGL(ga_kernel, dim3(64), dim3(256), 0, stream, out, ws);
  hipLaunchKernelGGL(gb_kernel, dim3(8), dim3(256), 0, stream, ws);
  hipLaunchKernelGGL(fuseda_kernel, dim3(256), dim3(512), 0, stream, out, ws);
  hipLaunchKernelGGL(fusedb_kernel, dim3(4096), dim3(256), 0, stream, out, ws);
}